// Round 3
// baseline (1285.834 us; speedup 1.0000x reference)
//
#include <hip/hip_runtime.h>
#include <math.h>

// Problem dims (fixed)
#define B_   128
#define L_   256
#define H_   128
#define H2_  256
#define VS_  256
#define TOK_ (B_ * L_)   // 32768

__device__ __forceinline__ float fma4(float4 a, float4 b, float acc) {
    acc = fmaf(a.x, b.x, acc);
    acc = fmaf(a.y, b.y, acc);
    acc = fmaf(a.z, b.z, acc);
    acc = fmaf(a.w, b.w, acc);
    return acc;
}

// ---------------- DPP cross-lane helpers (VALU-latency, no LDS) -------------
template <int CTRL>
__device__ __forceinline__ float dpp_add(float x) {
    int y = __builtin_amdgcn_update_dpp(0, __float_as_int(x), CTRL, 0xf, 0xf, true);
    return x + __int_as_float(y);
}
// Full 64-lane sum; total lands in lane 63.
__device__ __forceinline__ float wave_sum(float x) {
    x = dpp_add<0x111>(x);  // row_shr:1
    x = dpp_add<0x112>(x);  // row_shr:2
    x = dpp_add<0x114>(x);  // row_shr:4
    x = dpp_add<0x118>(x);  // row_shr:8
    x = dpp_add<0x142>(x);  // row_bcast:15
    x = dpp_add<0x143>(x);  // row_bcast:31
    return x;
}
// Sum over the 4 lanes of each quad (xor1 then xor2 via quad_perm).
__device__ __forceinline__ float quad_sum(float x) {
    x = dpp_add<0xB1>(x);   // quad_perm [1,0,3,2]
    x = dpp_add<0x4E>(x);   // quad_perm [2,3,0,1]
    return x;
}

// LDS index swizzles for k_ffn (unchanged from round 1)
#define HIDX(row, c4) ((row) * 32 + ((c4) ^ (((row) >> 2) & 7)))
#define WIDX(oc, k4)  ((oc) * 16 + ((k4) ^ (((oc) >> 2) & 15)))
#define YIDX(row, y4) ((row) * 16 + ((y4) ^ (((row) >> 2) & 15)))

// ---------------------------------------------------------------------------
// Kernel 1: fused  h = embed[seq];  f = relu(h@W1^T+b1)@W2^T+b2;
//                  x = h+f;  hln = LN(x)*gamma+beta;  K = hln@Wk^T
// (unchanged from round 1)
// ---------------------------------------------------------------------------
__global__ __launch_bounds__(256, 2) void k_ffn(
    const int* __restrict__ seq, const float* __restrict__ embed,
    const float* __restrict__ W1, const float* __restrict__ b1,
    const float* __restrict__ W2, const float* __restrict__ b2,
    const float* __restrict__ gamma, const float* __restrict__ beta,
    const float* __restrict__ Wk, float* __restrict__ Kout)
{
    __shared__ float4 sh_h[64 * 32];
    __shared__ float4 sh_w[64 * 16];
    __shared__ float4 sh_y[64 * 16];

    const int tid  = threadIdx.x;
    const int tc   = tid & 15;
    const int tr   = tid >> 4;
    const int tok0 = blockIdx.x * 64;

    const float4* embed4 = (const float4*)embed;
    const float4* W1_4   = (const float4*)W1;
    const float4* W2_4   = (const float4*)W2;
    const float4* Wk_4   = (const float4*)Wk;
    const float4* b1_4   = (const float4*)b1;
    const float4* b2_4   = (const float4*)b2;
    const float4* g_4    = (const float4*)gamma;
    const float4* be_4   = (const float4*)beta;

    #pragma unroll
    for (int f = tid; f < 2048; f += 256) {
        int row = f >> 5, c4 = f & 31;
        int idx = seq[tok0 + row];
        sh_h[HIDX(row, c4)] = embed4[idx * 32 + c4];
    }
    __syncthreads();

    float xacc[4][2][4];
    #pragma unroll
    for (int i = 0; i < 4; ++i)
        #pragma unroll
        for (int xh = 0; xh < 2; ++xh)
            #pragma unroll
            for (int j = 0; j < 4; ++j) xacc[i][xh][j] = 0.f;

    for (int nt = 0; nt < 4; ++nt) {
        float acc1[4][4];
        #pragma unroll
        for (int i = 0; i < 4; ++i)
            #pragma unroll
            for (int j = 0; j < 4; ++j) acc1[i][j] = 0.f;

        for (int kt = 0; kt < 2; ++kt) {
            #pragma unroll
            for (int f = tid; f < 1024; f += 256) {
                int oc = f >> 4, k4 = f & 15;
                sh_w[WIDX(oc, k4)] = W1_4[(nt * 64 + oc) * 32 + kt * 16 + k4];
            }
            __syncthreads();
            #pragma unroll 4
            for (int k4i = 0; k4i < 16; ++k4i) {
                float4 a4[4], b4[4];
                #pragma unroll
                for (int i = 0; i < 4; ++i) a4[i] = sh_h[HIDX(tr * 4 + i, kt * 16 + k4i)];
                #pragma unroll
                for (int j = 0; j < 4; ++j) b4[j] = sh_w[WIDX(tc * 4 + j, k4i)];
                #pragma unroll
                for (int i = 0; i < 4; ++i)
                    #pragma unroll
                    for (int j = 0; j < 4; ++j) acc1[i][j] = fma4(a4[i], b4[j], acc1[i][j]);
            }
            __syncthreads();
        }
        {
            float4 bv = b1_4[nt * 16 + tc];
            #pragma unroll
            for (int i = 0; i < 4; ++i) {
                float4 y;
                y.x = fmaxf(acc1[i][0] + bv.x, 0.f);
                y.y = fmaxf(acc1[i][1] + bv.y, 0.f);
                y.z = fmaxf(acc1[i][2] + bv.z, 0.f);
                y.w = fmaxf(acc1[i][3] + bv.w, 0.f);
                sh_y[YIDX(tr * 4 + i, tc)] = y;
            }
        }
        __syncthreads();

        #pragma unroll
        for (int xh = 0; xh < 2; ++xh) {
            #pragma unroll
            for (int f = tid; f < 1024; f += 256) {
                int oc = f >> 4, y4 = f & 15;
                sh_w[WIDX(oc, y4)] = W2_4[(xh * 64 + oc) * 64 + nt * 16 + y4];
            }
            __syncthreads();
            #pragma unroll 4
            for (int y4i = 0; y4i < 16; ++y4i) {
                float4 a4[4], b4[4];
                #pragma unroll
                for (int i = 0; i < 4; ++i) a4[i] = sh_y[YIDX(tr * 4 + i, y4i)];
                #pragma unroll
                for (int j = 0; j < 4; ++j) b4[j] = sh_w[WIDX(tc * 4 + j, y4i)];
                #pragma unroll
                for (int i = 0; i < 4; ++i)
                    #pragma unroll
                    for (int j = 0; j < 4; ++j) xacc[i][xh][j] = fma4(a4[i], b4[j], xacc[i][xh][j]);
            }
            __syncthreads();
        }
    }

    #pragma unroll
    for (int xh = 0; xh < 2; ++xh) {
        float4 bv = b2_4[xh * 16 + tc];
        int c4 = xh * 16 + tc;
        #pragma unroll
        for (int i = 0; i < 4; ++i) {
            float4 h4 = sh_h[HIDX(tr * 4 + i, c4)];
            h4.x += xacc[i][xh][0] + bv.x;
            h4.y += xacc[i][xh][1] + bv.y;
            h4.z += xacc[i][xh][2] + bv.z;
            h4.w += xacc[i][xh][3] + bv.w;
            sh_h[HIDX(tr * 4 + i, c4)] = h4;
        }
    }
    __syncthreads();

    {
        int row = tid >> 2, q = tid & 3;
        float s = 0.f, s2 = 0.f;
        #pragma unroll
        for (int u = 0; u < 8; ++u) {
            float4 v = sh_h[HIDX(row, q * 8 + u)];
            s  += v.x + v.y + v.z + v.w;
            s2 += v.x * v.x + v.y * v.y + v.z * v.z + v.w * v.w;
        }
        s  += __shfl_xor(s, 1);  s  += __shfl_xor(s, 2);
        s2 += __shfl_xor(s2, 1); s2 += __shfl_xor(s2, 2);
        float mu   = s * (1.f / 128.f);
        float var  = s2 * (1.f / 128.f) - mu * mu;
        float rstd = 1.f / sqrtf(var + 1e-5f);
        #pragma unroll
        for (int u = 0; u < 8; ++u) {
            int c4 = q * 8 + u;
            float4 v  = sh_h[HIDX(row, c4)];
            float4 gv = g_4[c4], bev = be_4[c4];
            v.x = (v.x - mu) * rstd * gv.x + bev.x;
            v.y = (v.y - mu) * rstd * gv.y + bev.y;
            v.z = (v.z - mu) * rstd * gv.z + bev.z;
            v.w = (v.w - mu) * rstd * gv.w + bev.w;
            sh_h[HIDX(row, c4)] = v;
        }
    }
    __syncthreads();

    for (int ch = 0; ch < 2; ++ch) {
        float acc[4][4];
        #pragma unroll
        for (int i = 0; i < 4; ++i)
            #pragma unroll
            for (int j = 0; j < 4; ++j) acc[i][j] = 0.f;

        for (int kt = 0; kt < 2; ++kt) {
            #pragma unroll
            for (int f = tid; f < 1024; f += 256) {
                int oc = f >> 4, k4 = f & 15;
                sh_w[WIDX(oc, k4)] = Wk_4[(ch * 64 + oc) * 32 + kt * 16 + k4];
            }
            __syncthreads();
            #pragma unroll 4
            for (int k4i = 0; k4i < 16; ++k4i) {
                float4 a4[4], b4[4];
                #pragma unroll
                for (int i = 0; i < 4; ++i) a4[i] = sh_h[HIDX(tr * 4 + i, kt * 16 + k4i)];
                #pragma unroll
                for (int j = 0; j < 4; ++j) b4[j] = sh_w[WIDX(tc * 4 + j, k4i)];
                #pragma unroll
                for (int i = 0; i < 4; ++i)
                    #pragma unroll
                    for (int j = 0; j < 4; ++j) acc[i][j] = fma4(a4[i], b4[j], acc[i][j]);
            }
            __syncthreads();
        }
        #pragma unroll
        for (int i = 0; i < 4; ++i) {
            float4 o = make_float4(acc[i][0], acc[i][1], acc[i][2], acc[i][3]);
            ((float4*)Kout)[(tok0 + tr * 4 + i) * 32 + ch * 16 + tc] = o;
        }
    }
}

// ---------------------------------------------------------------------------
// Kernel 2: gated delta-rule scan, rebuilt for critical-path latency.
//   - 4 waves/block; lane owns rows {w*32+2p, w*32+2p+1} x 32-col chunk cq.
//   - dot reduce = 2 quad_perm DPP adds; gate/n2/c reduces = 6-step DPP chain.
//   - ONE barrier per step (double-buffered sh_red, ring-8 LDS k buffer).
//   - matvec uses M_t (pre-update, issued before gate resolves);
//     dot_{t+1} = M_t*k_{t+1} + g_t*(rinv_t*c_t)*err_t  (rank-1 correction).
//   - k chunks cached in regs (staggered load -> conflict-free).
// ---------------------------------------------------------------------------
__global__ __launch_bounds__(256) void k_scan(
    const float* __restrict__ Kbuf, float* __restrict__ readout)
{
    __shared__ float4 sh_k[8][32];    // ring-8 of k vectors (128 f32 each)
    __shared__ float4 sh_red[2][4];   // per-wave {e2, n2_next, c} partials

    const int tid  = threadIdx.x;
    const int lane = tid & 63;
    const int w    = tid >> 6;        // wave id 0..3
    const int cq   = lane & 3;        // col chunk 0..3 (32 cols each)
    const int p    = lane >> 2;       // row pair 0..15
    const int b    = blockIdx.x;
    const float4* K4 = (const float4*)Kbuf;
    const size_t base = (size_t)b * 256;

    float4 m0[8], m1[8];              // M rows w*32+2p, w*32+2p+1; cols cq*32..+31
    #pragma unroll
    for (int u = 0; u < 8; ++u) {
        m0[u] = make_float4(0.f, 0.f, 0.f, 0.f);
        m1[u] = make_float4(0.f, 0.f, 0.f, 0.f);
    }

    // ---- prologue: stage k_0..k_3, issue prefetch of k_4,k_5 ----
    if (tid < 128) sh_k[tid >> 5][tid & 31] = K4[(base + (tid >> 5)) * 32 + (tid & 31)];
    float4 pfA = make_float4(0.f, 0.f, 0.f, 0.f);
    float4 pfB = make_float4(0.f, 0.f, 0.f, 0.f);
    if (tid < 32) {
        pfA = K4[(base + 4) * 32 + tid];
        pfB = K4[(base + 5) * 32 + tid];
    }
    __syncthreads();

    float4 kbA[8], kbB[8];            // k_t chunk register cache (double-buffered)
    {
        const float4* ks = sh_k[0] + cq * 8;
        #pragma unroll
        for (int u = 0; u < 8; ++u) { int uu = (u + cq) & 7; kbA[uu] = ks[uu]; }
    }
    float2 ks0 = ((const float2*)sh_k[0])[w * 16 + p];
    float err0 = ks0.x, err1 = ks0.y;  // err_0 = k_0 (dot_0 = 0)
    float rinv = 0.f, n2c = 0.f, dot0 = 0.f, dot1 = 0.f;

#define REGION(T, KBC, KBN, PF)                                                 \
  {                                                                             \
    const int t_ = (T);                                                         \
    /* partials: e2 (from err_t), n2(k_{t+1}), c = k_t . k_{t+1} */             \
    float e2p = (cq == 0) ? fmaf(err0, err0, err1 * err1) : 0.f;                \
    const float* kTn = (const float*)sh_k[(t_ + 1) & 7];                        \
    const float* kTc = (const float*)sh_k[t_ & 7];                              \
    float a_ = (lane < 32) ? kTn[w * 32 + lane] : 0.f;                          \
    float b_ = (lane < 32) ? kTc[w * 32 + lane] : 0.f;                          \
    float n2p = a_ * a_;                                                        \
    float cp  = a_ * b_;                                                        \
    e2p = wave_sum(e2p); n2p = wave_sum(n2p); cp = wave_sum(cp);                \
    if (lane == 63) sh_red[t_ & 1][w] = make_float4(e2p, n2p, cp, 0.f);         \
    if (tid < 32) {                                                             \
      sh_k[(t_ + 4) & 7][tid] = PF;                                             \
      int nidx = t_ + 6; if (nidx > 255) nidx = 255;                            \
      PF = K4[(base + nidx) * 32 + tid];                                        \
    }                                                                           \
    __syncthreads();                                                            \
    float4 r0 = sh_red[t_ & 1][0], r1 = sh_red[t_ & 1][1];                      \
    float4 r2 = sh_red[t_ & 1][2], r3 = sh_red[t_ & 1][3];                      \
    float e2t = (r0.x + r1.x) + (r2.x + r3.x);                                  \
    float n2n = (r0.y + r1.y) + (r2.y + r3.y);                                  \
    float cs  = (r0.z + r1.z) + (r2.z + r3.z);                                  \
    if (t_ == 0) { n2c = e2t; rinv = 1.f / fmaxf(sqrtf(n2c), 1e-12f); }         \
    bool g = (e2t >= 0.4f * 0.4f * n2c);                                        \
    /* rotate: k_{t+1} chunk -> regs (staggered, conflict-free) */              \
    {                                                                           \
      const float4* ks = sh_k[(t_ + 1) & 7] + cq * 8;                           \
      _Pragma("unroll")                                                         \
      for (int u = 0; u < 8; ++u) { int uu = (u + cq) & 7; KBN[uu] = ks[uu]; }  \
    }                                                                           \
    float2 kselfN = ((const float2*)sh_k[(t_ + 1) & 7])[w * 16 + p];            \
    /* matvec with M_t (pre-update): pre = M_t * k_{t+1} */                     \
    float pre0 = 0.f, pre1 = 0.f;                                               \
    _Pragma("unroll")                                                           \
    for (int u = 0; u < 8; ++u) {                                               \
      pre0 = fma4(m0[u], KBN[u], pre0);                                         \
      pre1 = fma4(m1[u], KBN[u], pre1);                                         \
    }                                                                           \
    /* update step t: M += (rinv_t*err_t) (x) k_t */                            \
    if (g) {                                                                    \
      float us0 = rinv * err0, us1 = rinv * err1;                               \
      _Pragma("unroll")                                                         \
      for (int u = 0; u < 8; ++u) {                                             \
        m0[u].x = fmaf(us0, KBC[u].x, m0[u].x);                                 \
        m0[u].y = fmaf(us0, KBC[u].y, m0[u].y);                                 \
        m0[u].z = fmaf(us0, KBC[u].z, m0[u].z);                                 \
        m0[u].w = fmaf(us0, KBC[u].w, m0[u].w);                                 \
        m1[u].x = fmaf(us1, KBC[u].x, m1[u].x);                                 \
        m1[u].y = fmaf(us1, KBC[u].y, m1[u].y);                                 \
        m1[u].z = fmaf(us1, KBC[u].z, m1[u].z);                                 \
        m1[u].w = fmaf(us1, KBC[u].w, m1[u].w);                                 \
      }                                                                         \
    }                                                                           \
    pre0 = quad_sum(pre0);                                                      \
    pre1 = quad_sum(pre1);                                                      \
    float cf = g ? rinv * cs : 0.f;                                             \
    float dn0 = fmaf(cf, err0, pre0);                                           \
    float dn1 = fmaf(cf, err1, pre1);                                           \
    float rn = 1.f / fmaxf(sqrtf(n2n), 1e-12f);                                 \
    err0 = kselfN.x - rn * dn0;                                                 \
    err1 = kselfN.y - rn * dn1;                                                 \
    rinv = rn; n2c = n2n; dot0 = dn0; dot1 = dn1;                               \
  }

    for (int tt = 0; tt < 254; tt += 2) {
        REGION(tt,     kbA, kbB, pfA);
        REGION(tt + 1, kbB, kbA, pfB);
    }
    REGION(254, kbA, kbB, pfA);
#undef REGION

    // After region 254: dot = M_255 * k_255 = the readout vector.
    if (cq == 0) {
        ((float2*)readout)[b * 64 + w * 16 + p] = make_float2(dot0, dot1);
    }
}

// ---------------------------------------------------------------------------
// Kernel 3: out = (read @ Wr^T + br) @ Wo^T + bo.  (unchanged)
// ---------------------------------------------------------------------------
__global__ __launch_bounds__(256) void k_out(
    const float* __restrict__ readout,
    const float* __restrict__ Wr, const float* __restrict__ br,
    const float* __restrict__ Wo, const float* __restrict__ bo,
    float* __restrict__ out)
{
    __shared__ float sh_rd[128];
    __shared__ float sh_r2[128];
    const int b = blockIdx.x, tid = threadIdx.x;

    if (tid < 32) ((float4*)sh_rd)[tid] = ((const float4*)readout)[b * 32 + tid];
    __syncthreads();

    {
        int i = tid >> 1, h = tid & 1;
        const float4* Wr4 = (const float4*)Wr;
        const float4* rd4 = (const float4*)sh_rd;
        float s = 0.f;
        #pragma unroll
        for (int u = 0; u < 16; ++u) s = fma4(rd4[h * 16 + u], Wr4[i * 32 + h * 16 + u], s);
        s += __shfl_xor(s, 1);
        if (h == 0) sh_r2[i] = s + br[i];
    }
    __syncthreads();

    {
        const float4* Wo4 = (const float4*)Wo;
        const float4* r24 = (const float4*)sh_r2;
        float acc = bo[tid];
        #pragma unroll
        for (int u = 0; u < 32; ++u) acc = fma4(r24[u], Wo4[tid * 32 + u], acc);
        out[b * 256 + tid] = acc;
    }
}

// ---------------------------------------------------------------------------
extern "C" void kernel_launch(void* const* d_in, const int* in_sizes, int n_in,
                              void* d_out, int out_size, void* d_ws, size_t ws_size,
                              hipStream_t stream) {
    const int*   seq   = (const int*)  d_in[0];
    const float* embed = (const float*)d_in[1];
    const float* W1    = (const float*)d_in[2];
    const float* b1    = (const float*)d_in[3];
    const float* W2    = (const float*)d_in[4];
    const float* b2    = (const float*)d_in[5];
    const float* gamma = (const float*)d_in[6];
    const float* beta  = (const float*)d_in[7];
    const float* Wk    = (const float*)d_in[8];
    const float* Wr    = (const float*)d_in[9];
    const float* br    = (const float*)d_in[10];
    const float* Wo    = (const float*)d_in[11];
    const float* bo    = (const float*)d_in[12];

    float* Kbuf    = (float*)d_ws;                    // 32768 * 128 f32 = 16 MiB
    float* readout = Kbuf + (size_t)TOK_ * H_;        // 128 * 128 f32
    float* out     = (float*)d_out;

    k_ffn <<<TOK_ / 64, 256, 0, stream>>>(seq, embed, W1, b1, W2, b2, gamma, beta, Wk, Kbuf);
    k_scan<<<B_,       256, 0, stream>>>(Kbuf, readout);
    k_out <<<B_,       256, 0, stream>>>(readout, Wr, br, Wo, bo, out);
}

// Round 5
// 272.762 us; speedup vs baseline: 4.7141x; 4.7141x over previous
//
#include <hip/hip_runtime.h>
#include <math.h>

// Problem dims (fixed)
#define B_   128
#define L_   256
#define H_   128
#define H2_  256
#define VS_  256
#define TOK_ (B_ * L_)   // 32768

__device__ __forceinline__ float fma4(float4 a, float4 b, float acc) {
    acc = fmaf(a.x, b.x, acc);
    acc = fmaf(a.y, b.y, acc);
    acc = fmaf(a.z, b.z, acc);
    acc = fmaf(a.w, b.w, acc);
    return acc;
}

// ---------------- DPP cross-lane helpers (VALU-latency, no LDS) -------------
template <int CTRL>
__device__ __forceinline__ float dpp_add(float x) {
    int y = __builtin_amdgcn_update_dpp(0, __float_as_int(x), CTRL, 0xf, 0xf, true);
    return x + __int_as_float(y);
}
// Full 64-lane sum; total lands in lane 63.
__device__ __forceinline__ float wave_sum(float x) {
    x = dpp_add<0x111>(x);  // row_shr:1
    x = dpp_add<0x112>(x);  // row_shr:2
    x = dpp_add<0x114>(x);  // row_shr:4
    x = dpp_add<0x118>(x);  // row_shr:8
    x = dpp_add<0x142>(x);  // row_bcast:15
    x = dpp_add<0x143>(x);  // row_bcast:31
    return x;
}
// Sum over the 4 lanes of each quad (butterfly -> valid in all 4 lanes).
__device__ __forceinline__ float quad_sum(float x) {
    x = dpp_add<0xB1>(x);   // quad_perm [1,0,3,2]
    x = dpp_add<0x4E>(x);   // quad_perm [2,3,0,1]
    return x;
}

// LDS index swizzles for k_ffn (unchanged)
#define HIDX(row, c4) ((row) * 32 + ((c4) ^ (((row) >> 2) & 7)))
#define WIDX(oc, k4)  ((oc) * 16 + ((k4) ^ (((oc) >> 2) & 15)))
#define YIDX(row, y4) ((row) * 16 + ((y4) ^ (((row) >> 2) & 15)))

// ---------------------------------------------------------------------------
// Kernel 1: fused  h = embed[seq];  f = relu(h@W1^T+b1)@W2^T+b2;
//                  x = h+f;  hln = LN(x)*gamma+beta;  K = hln@Wk^T
// (unchanged from round 1)
// ---------------------------------------------------------------------------
__global__ __launch_bounds__(256, 2) void k_ffn(
    const int* __restrict__ seq, const float* __restrict__ embed,
    const float* __restrict__ W1, const float* __restrict__ b1,
    const float* __restrict__ W2, const float* __restrict__ b2,
    const float* __restrict__ gamma, const float* __restrict__ beta,
    const float* __restrict__ Wk, float* __restrict__ Kout)
{
    __shared__ float4 sh_h[64 * 32];
    __shared__ float4 sh_w[64 * 16];
    __shared__ float4 sh_y[64 * 16];

    const int tid  = threadIdx.x;
    const int tc   = tid & 15;
    const int tr   = tid >> 4;
    const int tok0 = blockIdx.x * 64;

    const float4* embed4 = (const float4*)embed;
    const float4* W1_4   = (const float4*)W1;
    const float4* W2_4   = (const float4*)W2;
    const float4* Wk_4   = (const float4*)Wk;
    const float4* b1_4   = (const float4*)b1;
    const float4* b2_4   = (const float4*)b2;
    const float4* g_4    = (const float4*)gamma;
    const float4* be_4   = (const float4*)beta;

    #pragma unroll
    for (int f = tid; f < 2048; f += 256) {
        int row = f >> 5, c4 = f & 31;
        int idx = seq[tok0 + row];
        sh_h[HIDX(row, c4)] = embed4[idx * 32 + c4];
    }
    __syncthreads();

    float xacc[4][2][4];
    #pragma unroll
    for (int i = 0; i < 4; ++i)
        #pragma unroll
        for (int xh = 0; xh < 2; ++xh)
            #pragma unroll
            for (int j = 0; j < 4; ++j) xacc[i][xh][j] = 0.f;

    for (int nt = 0; nt < 4; ++nt) {
        float acc1[4][4];
        #pragma unroll
        for (int i = 0; i < 4; ++i)
            #pragma unroll
            for (int j = 0; j < 4; ++j) acc1[i][j] = 0.f;

        for (int kt = 0; kt < 2; ++kt) {
            #pragma unroll
            for (int f = tid; f < 1024; f += 256) {
                int oc = f >> 4, k4 = f & 15;
                sh_w[WIDX(oc, k4)] = W1_4[(nt * 64 + oc) * 32 + kt * 16 + k4];
            }
            __syncthreads();
            #pragma unroll 4
            for (int k4i = 0; k4i < 16; ++k4i) {
                float4 a4[4], b4[4];
                #pragma unroll
                for (int i = 0; i < 4; ++i) a4[i] = sh_h[HIDX(tr * 4 + i, kt * 16 + k4i)];
                #pragma unroll
                for (int j = 0; j < 4; ++j) b4[j] = sh_w[WIDX(tc * 4 + j, k4i)];
                #pragma unroll
                for (int i = 0; i < 4; ++i)
                    #pragma unroll
                    for (int j = 0; j < 4; ++j) acc1[i][j] = fma4(a4[i], b4[j], acc1[i][j]);
            }
            __syncthreads();
        }
        {
            float4 bv = b1_4[nt * 16 + tc];
            #pragma unroll
            for (int i = 0; i < 4; ++i) {
                float4 y;
                y.x = fmaxf(acc1[i][0] + bv.x, 0.f);
                y.y = fmaxf(acc1[i][1] + bv.y, 0.f);
                y.z = fmaxf(acc1[i][2] + bv.z, 0.f);
                y.w = fmaxf(acc1[i][3] + bv.w, 0.f);
                sh_y[YIDX(tr * 4 + i, tc)] = y;
            }
        }
        __syncthreads();

        #pragma unroll
        for (int xh = 0; xh < 2; ++xh) {
            #pragma unroll
            for (int f = tid; f < 1024; f += 256) {
                int oc = f >> 4, y4 = f & 15;
                sh_w[WIDX(oc, y4)] = W2_4[(xh * 64 + oc) * 64 + nt * 16 + y4];
            }
            __syncthreads();
            #pragma unroll 4
            for (int y4i = 0; y4i < 16; ++y4i) {
                float4 a4[4], b4[4];
                #pragma unroll
                for (int i = 0; i < 4; ++i) a4[i] = sh_y[YIDX(tr * 4 + i, y4i)];
                #pragma unroll
                for (int j = 0; j < 4; ++j) b4[j] = sh_w[WIDX(tc * 4 + j, y4i)];
                #pragma unroll
                for (int i = 0; i < 4; ++i)
                    #pragma unroll
                    for (int j = 0; j < 4; ++j) xacc[i][xh][j] = fma4(a4[i], b4[j], xacc[i][xh][j]);
            }
            __syncthreads();
        }
    }

    #pragma unroll
    for (int xh = 0; xh < 2; ++xh) {
        float4 bv = b2_4[xh * 16 + tc];
        int c4 = xh * 16 + tc;
        #pragma unroll
        for (int i = 0; i < 4; ++i) {
            float4 h4 = sh_h[HIDX(tr * 4 + i, c4)];
            h4.x += xacc[i][xh][0] + bv.x;
            h4.y += xacc[i][xh][1] + bv.y;
            h4.z += xacc[i][xh][2] + bv.z;
            h4.w += xacc[i][xh][3] + bv.w;
            sh_h[HIDX(tr * 4 + i, c4)] = h4;
        }
    }
    __syncthreads();

    {
        int row = tid >> 2, q = tid & 3;
        float s = 0.f, s2 = 0.f;
        #pragma unroll
        for (int u = 0; u < 8; ++u) {
            float4 v = sh_h[HIDX(row, q * 8 + u)];
            s  += v.x + v.y + v.z + v.w;
            s2 += v.x * v.x + v.y * v.y + v.z * v.z + v.w * v.w;
        }
        s  += __shfl_xor(s, 1);  s  += __shfl_xor(s, 2);
        s2 += __shfl_xor(s2, 1); s2 += __shfl_xor(s2, 2);
        float mu   = s * (1.f / 128.f);
        float var  = s2 * (1.f / 128.f) - mu * mu;
        float rstd = 1.f / sqrtf(var + 1e-5f);
        #pragma unroll
        for (int u = 0; u < 8; ++u) {
            int c4 = q * 8 + u;
            float4 v  = sh_h[HIDX(row, c4)];
            float4 gv = g_4[c4], bev = be_4[c4];
            v.x = (v.x - mu) * rstd * gv.x + bev.x;
            v.y = (v.y - mu) * rstd * gv.y + bev.y;
            v.z = (v.z - mu) * rstd * gv.z + bev.z;
            v.w = (v.w - mu) * rstd * gv.w + bev.w;
            sh_h[HIDX(row, c4)] = v;
        }
    }
    __syncthreads();

    for (int ch = 0; ch < 2; ++ch) {
        float acc[4][4];
        #pragma unroll
        for (int i = 0; i < 4; ++i)
            #pragma unroll
            for (int j = 0; j < 4; ++j) acc[i][j] = 0.f;

        for (int kt = 0; kt < 2; ++kt) {
            #pragma unroll
            for (int f = tid; f < 1024; f += 256) {
                int oc = f >> 4, k4 = f & 15;
                sh_w[WIDX(oc, k4)] = Wk_4[(ch * 64 + oc) * 32 + kt * 16 + k4];
            }
            __syncthreads();
            #pragma unroll 4
            for (int k4i = 0; k4i < 16; ++k4i) {
                float4 a4[4], b4[4];
                #pragma unroll
                for (int i = 0; i < 4; ++i) a4[i] = sh_h[HIDX(tr * 4 + i, kt * 16 + k4i)];
                #pragma unroll
                for (int j = 0; j < 4; ++j) b4[j] = sh_w[WIDX(tc * 4 + j, k4i)];
                #pragma unroll
                for (int i = 0; i < 4; ++i)
                    #pragma unroll
                    for (int j = 0; j < 4; ++j) acc[i][j] = fma4(a4[i], b4[j], acc[i][j]);
            }
            __syncthreads();
        }
        #pragma unroll
        for (int i = 0; i < 4; ++i) {
            float4 o = make_float4(acc[i][0], acc[i][1], acc[i][2], acc[i][3]);
            ((float4*)Kout)[(tok0 + tr * 4 + i) * 32 + ch * 16 + tc] = o;
        }
    }
}

// ---------------------------------------------------------------------------
// Kernel 2: gated delta-rule scan.
//   FIX vs R3: all register-array indices are compile-time static (rule #20);
//   the bank-conflict permutation moved to the LDS *source address*
//   (KBN[u] = ks[(u+cq)&7] — per-thread-constant register relabeling, math
//   invariant under the sum over u). Matvec+quad_sum moved pre-barrier
//   (depends only on M_t and k_{t+1}); post-barrier path = gate + update +
//   rank-1 correction.
// ---------------------------------------------------------------------------
__global__ __launch_bounds__(256) void k_scan(
    const float* __restrict__ Kbuf, float* __restrict__ readout)
{
    __shared__ float4 sh_k[8][32];    // ring-8 of k vectors (128 f32 each)
    __shared__ float4 sh_red[2][4];   // per-wave {e2, n2_next, c} partials

    const int tid  = threadIdx.x;
    const int lane = tid & 63;
    const int w    = tid >> 6;        // wave id 0..3
    const int cq   = lane & 3;        // col chunk 0..3 (32 cols each)
    const int p    = lane >> 2;       // row pair 0..15
    const int b    = blockIdx.x;
    const float4* K4 = (const float4*)Kbuf;
    const size_t base = (size_t)b * 256;

    // M rows {w*32+2p, w*32+2p+1}, cols cq*32..+31; per-thread labeling of the
    // 8 float4 sub-chunks is rotated by cq (consistent across matvec/update).
    float4 m0[8], m1[8];
    #pragma unroll
    for (int u = 0; u < 8; ++u) {
        m0[u] = make_float4(0.f, 0.f, 0.f, 0.f);
        m1[u] = make_float4(0.f, 0.f, 0.f, 0.f);
    }

    // ---- prologue: stage k_0..k_3, issue prefetch of k_4,k_5 ----
    if (tid < 128) sh_k[tid >> 5][tid & 31] = K4[(base + (tid >> 5)) * 32 + (tid & 31)];
    float4 pfA = make_float4(0.f, 0.f, 0.f, 0.f);
    float4 pfB = make_float4(0.f, 0.f, 0.f, 0.f);
    if (tid < 32) {
        pfA = K4[(base + 4) * 32 + tid];
        pfB = K4[(base + 5) * 32 + tid];
    }
    __syncthreads();

    float4 kbA[8], kbB[8];            // k_t chunk register cache (double-buffered)
    {
        const float4* ks = sh_k[0] + cq * 8;
        #pragma unroll
        for (int u = 0; u < 8; ++u) kbA[u] = ks[(u + cq) & 7];   // static dest
    }
    float2 ks0 = ((const float2*)sh_k[0])[w * 16 + p];
    float err0 = ks0.x, err1 = ks0.y;  // err_0 = k_0 (dot_0 = 0)
    float rinv = 0.f, n2c = 0.f, dot0 = 0.f, dot1 = 0.f;

#define REGION(T, KBC, KBN, PF)                                                 \
  {                                                                             \
    const int t_ = (T);                                                         \
    /* ---- pre-barrier ---- */                                                 \
    /* partials: e2 (from err_t), n2(k_{t+1}), c = k_t . k_{t+1} */             \
    float e2p = (cq == 0) ? fmaf(err0, err0, err1 * err1) : 0.f;                \
    const float* kTn = (const float*)sh_k[(t_ + 1) & 7];                        \
    const float* kTc = (const float*)sh_k[t_ & 7];                              \
    float a_ = (lane < 32) ? kTn[w * 32 + lane] : 0.f;                          \
    float b_ = (lane < 32) ? kTc[w * 32 + lane] : 0.f;                          \
    float n2p = a_ * a_;                                                        \
    float cp  = a_ * b_;                                                        \
    /* rotate k_{t+1} chunk -> regs: STATIC dest idx, permuted LDS src addr */  \
    {                                                                           \
      const float4* ks = sh_k[(t_ + 1) & 7] + cq * 8;                           \
      _Pragma("unroll")                                                         \
      for (int u = 0; u < 8; ++u) KBN[u] = ks[(u + cq) & 7];                    \
    }                                                                           \
    float2 kselfN = ((const float2*)sh_k[(t_ + 1) & 7])[w * 16 + p];            \
    /* matvec with M_t (needs no gate): pre = M_t * k_{t+1} */                  \
    float pre0 = 0.f, pre1 = 0.f;                                               \
    _Pragma("unroll")                                                           \
    for (int u = 0; u < 8; ++u) {                                               \
      pre0 = fma4(m0[u], KBN[u], pre0);                                         \
      pre1 = fma4(m1[u], KBN[u], pre1);                                         \
    }                                                                           \
    pre0 = quad_sum(pre0);                                                      \
    pre1 = quad_sum(pre1);                                                      \
    e2p = wave_sum(e2p); n2p = wave_sum(n2p); cp = wave_sum(cp);                \
    if (lane == 63) sh_red[t_ & 1][w] = make_float4(e2p, n2p, cp, 0.f);         \
    if (tid < 32) {                                                             \
      sh_k[(t_ + 4) & 7][tid] = PF;                                             \
      int nidx = t_ + 6; if (nidx > 255) nidx = 255;                            \
      PF = K4[(base + nidx) * 32 + tid];                                        \
    }                                                                           \
    __syncthreads();                                                            \
    /* ---- post-barrier ---- */                                                \
    float4 r0 = sh_red[t_ & 1][0], r1 = sh_red[t_ & 1][1];                      \
    float4 r2 = sh_red[t_ & 1][2], r3 = sh_red[t_ & 1][3];                      \
    float e2t = (r0.x + r1.x) + (r2.x + r3.x);                                  \
    float n2n = (r0.y + r1.y) + (r2.y + r3.y);                                  \
    float cs  = (r0.z + r1.z) + (r2.z + r3.z);                                  \
    if (t_ == 0) { n2c = e2t; rinv = 1.f / fmaxf(sqrtf(n2c), 1e-12f); }         \
    bool g = (e2t >= 0.4f * 0.4f * n2c);                                        \
    /* update step t: M += (rinv_t*err_t) (x) k_t */                            \
    if (g) {                                                                    \
      float us0 = rinv * err0, us1 = rinv * err1;                               \
      _Pragma("unroll")                                                         \
      for (int u = 0; u < 8; ++u) {                                             \
        m0[u].x = fmaf(us0, KBC[u].x, m0[u].x);                                 \
        m0[u].y = fmaf(us0, KBC[u].y, m0[u].y);                                 \
        m0[u].z = fmaf(us0, KBC[u].z, m0[u].z);                                 \
        m0[u].w = fmaf(us0, KBC[u].w, m0[u].w);                                 \
        m1[u].x = fmaf(us1, KBC[u].x, m1[u].x);                                 \
        m1[u].y = fmaf(us1, KBC[u].y, m1[u].y);                                 \
        m1[u].z = fmaf(us1, KBC[u].z, m1[u].z);                                 \
        m1[u].w = fmaf(us1, KBC[u].w, m1[u].w);                                 \
      }                                                                         \
    }                                                                           \
    /* rank-1 correction: dot_{t+1} = pre + g*rinv_t*(k_t.k_{t+1})*err_t */     \
    float cf = g ? rinv * cs : 0.f;                                             \
    float dn0 = fmaf(cf, err0, pre0);                                           \
    float dn1 = fmaf(cf, err1, pre1);                                           \
    float rn = 1.f / fmaxf(sqrtf(n2n), 1e-12f);                                 \
    err0 = kselfN.x - rn * dn0;                                                 \
    err1 = kselfN.y - rn * dn1;                                                 \
    rinv = rn; n2c = n2n; dot0 = dn0; dot1 = dn1;                               \
  }

    for (int tt = 0; tt < 254; tt += 2) {
        REGION(tt,     kbA, kbB, pfA);
        REGION(tt + 1, kbB, kbA, pfB);
    }
    REGION(254, kbA, kbB, pfA);
#undef REGION

    // After region 254: dot = M_255 * k_255 = the readout vector.
    if (cq == 0) {
        ((float2*)readout)[b * 64 + w * 16 + p] = make_float2(dot0, dot1);
    }
}

// ---------------------------------------------------------------------------
// Kernel 3: out = (read @ Wr^T + br) @ Wo^T + bo.  (unchanged)
// ---------------------------------------------------------------------------
__global__ __launch_bounds__(256) void k_out(
    const float* __restrict__ readout,
    const float* __restrict__ Wr, const float* __restrict__ br,
    const float* __restrict__ Wo, const float* __restrict__ bo,
    float* __restrict__ out)
{
    __shared__ float sh_rd[128];
    __shared__ float sh_r2[128];
    const int b = blockIdx.x, tid = threadIdx.x;

    if (tid < 32) ((float4*)sh_rd)[tid] = ((const float4*)readout)[b * 32 + tid];
    __syncthreads();

    {
        int i = tid >> 1, h = tid & 1;
        const float4* Wr4 = (const float4*)Wr;
        const float4* rd4 = (const float4*)sh_rd;
        float s = 0.f;
        #pragma unroll
        for (int u = 0; u < 16; ++u) s = fma4(rd4[h * 16 + u], Wr4[i * 32 + h * 16 + u], s);
        s += __shfl_xor(s, 1);
        if (h == 0) sh_r2[i] = s + br[i];
    }
    __syncthreads();

    {
        const float4* Wo4 = (const float4*)Wo;
        const float4* r24 = (const float4*)sh_r2;
        float acc = bo[tid];
        #pragma unroll
        for (int u = 0; u < 32; ++u) acc = fma4(r24[u], Wo4[tid * 32 + u], acc);
        out[b * 256 + tid] = acc;
    }
}

// ---------------------------------------------------------------------------
extern "C" void kernel_launch(void* const* d_in, const int* in_sizes, int n_in,
                              void* d_out, int out_size, void* d_ws, size_t ws_size,
                              hipStream_t stream) {
    const int*   seq   = (const int*)  d_in[0];
    const float* embed = (const float*)d_in[1];
    const float* W1    = (const float*)d_in[2];
    const float* b1    = (const float*)d_in[3];
    const float* W2    = (const float*)d_in[4];
    const float* b2    = (const float*)d_in[5];
    const float* gamma = (const float*)d_in[6];
    const float* beta  = (const float*)d_in[7];
    const float* Wk    = (const float*)d_in[8];
    const float* Wr    = (const float*)d_in[9];
    const float* br    = (const float*)d_in[10];
    const float* Wo    = (const float*)d_in[11];
    const float* bo    = (const float*)d_in[12];

    float* Kbuf    = (float*)d_ws;                    // 32768 * 128 f32 = 16 MiB
    float* readout = Kbuf + (size_t)TOK_ * H_;        // 128 * 128 f32
    float* out     = (float*)d_out;

    k_ffn <<<TOK_ / 64, 256, 0, stream>>>(seq, embed, W1, b1, W2, b2, gamma, beta, Wk, Kbuf);
    k_scan<<<B_,       256, 0, stream>>>(Kbuf, readout);
    k_out <<<B_,       256, 0, stream>>>(readout, Wr, br, Wo, bo, out);
}

// Round 6
// 230.808 us; speedup vs baseline: 5.5710x; 1.1818x over previous
//
#include <hip/hip_runtime.h>
#include <math.h>

// Problem dims (fixed)
#define B_   128
#define L_   256
#define H_   128
#define H2_  256
#define VS_  256
#define TOK_ (B_ * L_)   // 32768

__device__ __forceinline__ float fma4(float4 a, float4 b, float acc) {
    acc = fmaf(a.x, b.x, acc);
    acc = fmaf(a.y, b.y, acc);
    acc = fmaf(a.z, b.z, acc);
    acc = fmaf(a.w, b.w, acc);
    return acc;
}

// ---------------- DPP cross-lane helpers (VALU-latency, no LDS) -------------
template <int CTRL>
__device__ __forceinline__ float dpp_add(float x) {
    int y = __builtin_amdgcn_update_dpp(0, __float_as_int(x), CTRL, 0xf, 0xf, true);
    return x + __int_as_float(y);
}
// Full 64-lane sum; total lands in lane 63.
__device__ __forceinline__ float wave_sum(float x) {
    x = dpp_add<0x111>(x);  // row_shr:1
    x = dpp_add<0x112>(x);  // row_shr:2
    x = dpp_add<0x114>(x);  // row_shr:4
    x = dpp_add<0x118>(x);  // row_shr:8
    x = dpp_add<0x142>(x);  // row_bcast:15
    x = dpp_add<0x143>(x);  // row_bcast:31
    return x;
}
// Sum over the 4 lanes of each quad (butterfly -> valid in all 4 lanes).
__device__ __forceinline__ float quad_sum(float x) {
    x = dpp_add<0xB1>(x);   // quad_perm [1,0,3,2]
    x = dpp_add<0x4E>(x);   // quad_perm [2,3,0,1]
    return x;
}

// LDS index swizzles for k_ffn (unchanged)
#define HIDX(row, c4) ((row) * 32 + ((c4) ^ (((row) >> 2) & 7)))
#define WIDX(oc, k4)  ((oc) * 16 + ((k4) ^ (((oc) >> 2) & 15)))
#define YIDX(row, y4) ((row) * 16 + ((y4) ^ (((row) >> 2) & 15)))

// ---------------------------------------------------------------------------
// Kernel 1: fused  h = embed[seq];  f = relu(h@W1^T+b1)@W2^T+b2;
//                  x = h+f;  hln = LN(x)*gamma+beta;  K = hln@Wk^T
// (unchanged from round 1)
// ---------------------------------------------------------------------------
__global__ __launch_bounds__(256, 2) void k_ffn(
    const int* __restrict__ seq, const float* __restrict__ embed,
    const float* __restrict__ W1, const float* __restrict__ b1,
    const float* __restrict__ W2, const float* __restrict__ b2,
    const float* __restrict__ gamma, const float* __restrict__ beta,
    const float* __restrict__ Wk, float* __restrict__ Kout)
{
    __shared__ float4 sh_h[64 * 32];
    __shared__ float4 sh_w[64 * 16];
    __shared__ float4 sh_y[64 * 16];

    const int tid  = threadIdx.x;
    const int tc   = tid & 15;
    const int tr   = tid >> 4;
    const int tok0 = blockIdx.x * 64;

    const float4* embed4 = (const float4*)embed;
    const float4* W1_4   = (const float4*)W1;
    const float4* W2_4   = (const float4*)W2;
    const float4* Wk_4   = (const float4*)Wk;
    const float4* b1_4   = (const float4*)b1;
    const float4* b2_4   = (const float4*)b2;
    const float4* g_4    = (const float4*)gamma;
    const float4* be_4   = (const float4*)beta;

    #pragma unroll
    for (int f = tid; f < 2048; f += 256) {
        int row = f >> 5, c4 = f & 31;
        int idx = seq[tok0 + row];
        sh_h[HIDX(row, c4)] = embed4[idx * 32 + c4];
    }
    __syncthreads();

    float xacc[4][2][4];
    #pragma unroll
    for (int i = 0; i < 4; ++i)
        #pragma unroll
        for (int xh = 0; xh < 2; ++xh)
            #pragma unroll
            for (int j = 0; j < 4; ++j) xacc[i][xh][j] = 0.f;

    for (int nt = 0; nt < 4; ++nt) {
        float acc1[4][4];
        #pragma unroll
        for (int i = 0; i < 4; ++i)
            #pragma unroll
            for (int j = 0; j < 4; ++j) acc1[i][j] = 0.f;

        for (int kt = 0; kt < 2; ++kt) {
            #pragma unroll
            for (int f = tid; f < 1024; f += 256) {
                int oc = f >> 4, k4 = f & 15;
                sh_w[WIDX(oc, k4)] = W1_4[(nt * 64 + oc) * 32 + kt * 16 + k4];
            }
            __syncthreads();
            #pragma unroll 4
            for (int k4i = 0; k4i < 16; ++k4i) {
                float4 a4[4], b4[4];
                #pragma unroll
                for (int i = 0; i < 4; ++i) a4[i] = sh_h[HIDX(tr * 4 + i, kt * 16 + k4i)];
                #pragma unroll
                for (int j = 0; j < 4; ++j) b4[j] = sh_w[WIDX(tc * 4 + j, k4i)];
                #pragma unroll
                for (int i = 0; i < 4; ++i)
                    #pragma unroll
                    for (int j = 0; j < 4; ++j) acc1[i][j] = fma4(a4[i], b4[j], acc1[i][j]);
            }
            __syncthreads();
        }
        {
            float4 bv = b1_4[nt * 16 + tc];
            #pragma unroll
            for (int i = 0; i < 4; ++i) {
                float4 y;
                y.x = fmaxf(acc1[i][0] + bv.x, 0.f);
                y.y = fmaxf(acc1[i][1] + bv.y, 0.f);
                y.z = fmaxf(acc1[i][2] + bv.z, 0.f);
                y.w = fmaxf(acc1[i][3] + bv.w, 0.f);
                sh_y[YIDX(tr * 4 + i, tc)] = y;
            }
        }
        __syncthreads();

        #pragma unroll
        for (int xh = 0; xh < 2; ++xh) {
            #pragma unroll
            for (int f = tid; f < 1024; f += 256) {
                int oc = f >> 4, y4 = f & 15;
                sh_w[WIDX(oc, y4)] = W2_4[(xh * 64 + oc) * 64 + nt * 16 + y4];
            }
            __syncthreads();
            #pragma unroll 4
            for (int y4i = 0; y4i < 16; ++y4i) {
                float4 a4[4], b4[4];
                #pragma unroll
                for (int i = 0; i < 4; ++i) a4[i] = sh_y[YIDX(tr * 4 + i, y4i)];
                #pragma unroll
                for (int j = 0; j < 4; ++j) b4[j] = sh_w[WIDX(tc * 4 + j, y4i)];
                #pragma unroll
                for (int i = 0; i < 4; ++i)
                    #pragma unroll
                    for (int j = 0; j < 4; ++j) xacc[i][xh][j] = fma4(a4[i], b4[j], xacc[i][xh][j]);
            }
            __syncthreads();
        }
    }

    #pragma unroll
    for (int xh = 0; xh < 2; ++xh) {
        float4 bv = b2_4[xh * 16 + tc];
        int c4 = xh * 16 + tc;
        #pragma unroll
        for (int i = 0; i < 4; ++i) {
            float4 h4 = sh_h[HIDX(tr * 4 + i, c4)];
            h4.x += xacc[i][xh][0] + bv.x;
            h4.y += xacc[i][xh][1] + bv.y;
            h4.z += xacc[i][xh][2] + bv.z;
            h4.w += xacc[i][xh][3] + bv.w;
            sh_h[HIDX(tr * 4 + i, c4)] = h4;
        }
    }
    __syncthreads();

    {
        int row = tid >> 2, q = tid & 3;
        float s = 0.f, s2 = 0.f;
        #pragma unroll
        for (int u = 0; u < 8; ++u) {
            float4 v = sh_h[HIDX(row, q * 8 + u)];
            s  += v.x + v.y + v.z + v.w;
            s2 += v.x * v.x + v.y * v.y + v.z * v.z + v.w * v.w;
        }
        s  += __shfl_xor(s, 1);  s  += __shfl_xor(s, 2);
        s2 += __shfl_xor(s2, 1); s2 += __shfl_xor(s2, 2);
        float mu   = s * (1.f / 128.f);
        float var  = s2 * (1.f / 128.f) - mu * mu;
        float rstd = 1.f / sqrtf(var + 1e-5f);
        #pragma unroll
        for (int u = 0; u < 8; ++u) {
            int c4 = q * 8 + u;
            float4 v  = sh_h[HIDX(row, c4)];
            float4 gv = g_4[c4], bev = be_4[c4];
            v.x = (v.x - mu) * rstd * gv.x + bev.x;
            v.y = (v.y - mu) * rstd * gv.y + bev.y;
            v.z = (v.z - mu) * rstd * gv.z + bev.z;
            v.w = (v.w - mu) * rstd * gv.w + bev.w;
            sh_h[HIDX(row, c4)] = v;
        }
    }
    __syncthreads();

    for (int ch = 0; ch < 2; ++ch) {
        float acc[4][4];
        #pragma unroll
        for (int i = 0; i < 4; ++i)
            #pragma unroll
            for (int j = 0; j < 4; ++j) acc[i][j] = 0.f;

        for (int kt = 0; kt < 2; ++kt) {
            #pragma unroll
            for (int f = tid; f < 1024; f += 256) {
                int oc = f >> 4, k4 = f & 15;
                sh_w[WIDX(oc, k4)] = Wk_4[(ch * 64 + oc) * 32 + kt * 16 + k4];
            }
            __syncthreads();
            #pragma unroll 4
            for (int k4i = 0; k4i < 16; ++k4i) {
                float4 a4[4], b4[4];
                #pragma unroll
                for (int i = 0; i < 4; ++i) a4[i] = sh_h[HIDX(tr * 4 + i, kt * 16 + k4i)];
                #pragma unroll
                for (int j = 0; j < 4; ++j) b4[j] = sh_w[WIDX(tc * 4 + j, k4i)];
                #pragma unroll
                for (int i = 0; i < 4; ++i)
                    #pragma unroll
                    for (int j = 0; j < 4; ++j) acc[i][j] = fma4(a4[i], b4[j], acc[i][j]);
            }
            __syncthreads();
        }
        #pragma unroll
        for (int i = 0; i < 4; ++i) {
            float4 o = make_float4(acc[i][0], acc[i][1], acc[i][2], acc[i][3]);
            ((float4*)Kout)[(tok0 + tr * 4 + i) * 32 + ch * 16 + tc] = o;
        }
    }
}

// ---------------------------------------------------------------------------
// Kernel 2: gated delta-rule scan, VMEM-free main loop.
//   All 256 k-vectors staged to dynamic LDS in the prologue (128 KiB; one
//   block per CU so 134 KiB LDS is fine). Per-t scalars precomputed:
//     rna[t] = 1/max(||k_t||,eps), thr[t] = 0.16*||k_t||^2,
//     rc[t]  = rna[t]*(k_t . k_{t+1}).
//   Per step: ONE wave_sum (e2), one barrier (vmcnt-free), static-index
//   register caches, matvec uses M_t + rank-1 correction (R4 scheme).
// ---------------------------------------------------------------------------
__global__ __launch_bounds__(256) void k_scan(
    const float* __restrict__ Kbuf, float* __restrict__ readout)
{
    extern __shared__ float smem_f[];
    float4* shk4 = (float4*)smem_f;          // [256][32] float4 = 128 KiB
    float*  rna  = smem_f + 32768;           // [256]
    float*  thr  = rna + 256;                // [256]
    float*  rc_  = thr + 256;                // [256]
    float*  red  = rc_ + 256;                // [2][4], 16B-aligned (byte 134144)

    const int tid  = threadIdx.x;
    const int lane = tid & 63;
    const int w    = tid >> 6;        // wave id 0..3
    const int cq   = lane & 3;        // col chunk 0..3 (32 cols each)
    const int p    = lane >> 2;       // row pair 0..15
    const int b    = blockIdx.x;
    const float4* K4 = (const float4*)Kbuf;
    const size_t base32 = (size_t)b * 256 * 32;

    // ---- prologue 1: stage ALL k vectors (coalesced, one vmcnt drain) ----
    for (int f = tid; f < 8192; f += 256) shk4[f] = K4[base32 + f];
    __syncthreads();

    // ---- prologue 2: per-row norms + neighbor dots (16 threads per row) ----
    {
        int rr = tid >> 4, cc = tid & 15;
        for (int it = 0; it < 16; ++it) {
            int t  = it * 16 + rr;
            int tn = (t < 255) ? t + 1 : 255;
            float4 a0 = shk4[t  * 32 + cc], a1 = shk4[t  * 32 + 16 + cc];
            float4 b0 = shk4[tn * 32 + cc], b1 = shk4[tn * 32 + 16 + cc];
            float n2p = fma4(a1, a1, fma4(a0, a0, 0.f));
            float cp  = fma4(a1, b1, fma4(a0, b0, 0.f));
            n2p += __shfl_xor(n2p, 1); n2p += __shfl_xor(n2p, 2);
            n2p += __shfl_xor(n2p, 4); n2p += __shfl_xor(n2p, 8);
            cp  += __shfl_xor(cp, 1);  cp  += __shfl_xor(cp, 2);
            cp  += __shfl_xor(cp, 4);  cp  += __shfl_xor(cp, 8);
            if (cc == 0) {
                float ri = 1.f / fmaxf(sqrtf(n2p), 1e-12f);
                rna[t] = ri;
                thr[t] = 0.16f * n2p;
                rc_[t] = ri * cp;
            }
        }
    }
    __syncthreads();

    // M rows {w*32+2p, w*32+2p+1}, cols cq*32..+31; per-thread labeling of the
    // 8 float4 sub-chunks is rotated by cq (consistent matvec/update).
    float4 m0[8], m1[8];
    #pragma unroll
    for (int u = 0; u < 8; ++u) {
        m0[u] = make_float4(0.f, 0.f, 0.f, 0.f);
        m1[u] = make_float4(0.f, 0.f, 0.f, 0.f);
    }

    float4 kbA[8], kbB[8];            // k_t chunk register cache (double-buffered)
    {
        const float4* ks = shk4 + cq * 8;
        #pragma unroll
        for (int u = 0; u < 8; ++u) kbA[u] = ks[(u + cq) & 7];   // static dest
    }
    float2 ks0 = ((const float2*)shk4)[w * 16 + p];
    float err0 = ks0.x, err1 = ks0.y;  // err_0 = k_0 (dot_0 = 0)
    float dot0 = 0.f, dot1 = 0.f;

#define REGION(T, KBC, KBN)                                                     \
  {                                                                             \
    const int t_ = (T);                                                         \
    /* ---- pre-barrier ---- */                                                 \
    float e2p = (cq == 0) ? fmaf(err0, err0, err1 * err1) : 0.f;                \
    float thr_t = thr[t_];                                                      \
    float rct   = rc_[t_];                                                      \
    float rit   = rna[t_];                                                      \
    float rin   = rna[t_ + 1];                                                  \
    /* rotate k_{t+1} chunk -> regs: STATIC dest idx, permuted LDS src addr */  \
    {                                                                           \
      const float4* ks = shk4 + (t_ + 1) * 32 + cq * 8;                         \
      _Pragma("unroll")                                                         \
      for (int u = 0; u < 8; ++u) KBN[u] = ks[(u + cq) & 7];                    \
    }                                                                           \
    float2 kselfN = ((const float2*)(shk4 + (t_ + 1) * 32))[w * 16 + p];        \
    /* matvec with M_t (needs no gate): pre = M_t * k_{t+1} */                  \
    float pre0 = 0.f, pre1 = 0.f;                                               \
    _Pragma("unroll")                                                           \
    for (int u = 0; u < 8; ++u) {                                               \
      pre0 = fma4(m0[u], KBN[u], pre0);                                         \
      pre1 = fma4(m1[u], KBN[u], pre1);                                         \
    }                                                                           \
    pre0 = quad_sum(pre0);                                                      \
    pre1 = quad_sum(pre1);                                                      \
    e2p = wave_sum(e2p);                                                        \
    if (lane == 63) red[(t_ & 1) * 4 + w] = e2p;                                \
    __syncthreads();                                                            \
    /* ---- post-barrier ---- */                                                \
    float4 rv = *(const float4*)&red[(t_ & 1) * 4];                             \
    float e2t = (rv.x + rv.y) + (rv.z + rv.w);                                  \
    bool g = (e2t >= thr_t);                                                    \
    /* update step t: M += (rna[t]*err_t) (x) k_t */                            \
    if (g) {                                                                    \
      float us0 = rit * err0, us1 = rit * err1;                                 \
      _Pragma("unroll")                                                         \
      for (int u = 0; u < 8; ++u) {                                             \
        m0[u].x = fmaf(us0, KBC[u].x, m0[u].x);                                 \
        m0[u].y = fmaf(us0, KBC[u].y, m0[u].y);                                 \
        m0[u].z = fmaf(us0, KBC[u].z, m0[u].z);                                 \
        m0[u].w = fmaf(us0, KBC[u].w, m0[u].w);                                 \
        m1[u].x = fmaf(us1, KBC[u].x, m1[u].x);                                 \
        m1[u].y = fmaf(us1, KBC[u].y, m1[u].y);                                 \
        m1[u].z = fmaf(us1, KBC[u].z, m1[u].z);                                 \
        m1[u].w = fmaf(us1, KBC[u].w, m1[u].w);                                 \
      }                                                                         \
    }                                                                           \
    /* rank-1 correction: dot_{t+1} = pre + g*rc[t]*err_t */                    \
    float cf = g ? rct : 0.f;                                                   \
    float dn0 = fmaf(cf, err0, pre0);                                           \
    float dn1 = fmaf(cf, err1, pre1);                                           \
    err0 = kselfN.x - rin * dn0;                                                \
    err1 = kselfN.y - rin * dn1;                                                \
    dot0 = dn0; dot1 = dn1;                                                     \
  }

    for (int tt = 0; tt < 254; tt += 2) {
        REGION(tt,     kbA, kbB);
        REGION(tt + 1, kbB, kbA);
    }
    REGION(254, kbA, kbB);
#undef REGION

    // After region 254: dot = M_255 * k_255 = the readout vector.
    if (cq == 0) {
        ((float2*)readout)[b * 64 + w * 16 + p] = make_float2(dot0, dot1);
    }
}

// ---------------------------------------------------------------------------
// Kernel 3: out = (read @ Wr^T + br) @ Wo^T + bo.  (unchanged)
// ---------------------------------------------------------------------------
__global__ __launch_bounds__(256) void k_out(
    const float* __restrict__ readout,
    const float* __restrict__ Wr, const float* __restrict__ br,
    const float* __restrict__ Wo, const float* __restrict__ bo,
    float* __restrict__ out)
{
    __shared__ float sh_rd[128];
    __shared__ float sh_r2[128];
    const int b = blockIdx.x, tid = threadIdx.x;

    if (tid < 32) ((float4*)sh_rd)[tid] = ((const float4*)readout)[b * 32 + tid];
    __syncthreads();

    {
        int i = tid >> 1, h = tid & 1;
        const float4* Wr4 = (const float4*)Wr;
        const float4* rd4 = (const float4*)sh_rd;
        float s = 0.f;
        #pragma unroll
        for (int u = 0; u < 16; ++u) s = fma4(rd4[h * 16 + u], Wr4[i * 32 + h * 16 + u], s);
        s += __shfl_xor(s, 1);
        if (h == 0) sh_r2[i] = s + br[i];
    }
    __syncthreads();

    {
        const float4* Wo4 = (const float4*)Wo;
        const float4* r24 = (const float4*)sh_r2;
        float acc = bo[tid];
        #pragma unroll
        for (int u = 0; u < 32; ++u) acc = fma4(r24[u], Wo4[tid * 32 + u], acc);
        out[b * 256 + tid] = acc;
    }
}

// ---------------------------------------------------------------------------
extern "C" void kernel_launch(void* const* d_in, const int* in_sizes, int n_in,
                              void* d_out, int out_size, void* d_ws, size_t ws_size,
                              hipStream_t stream) {
    const int*   seq   = (const int*)  d_in[0];
    const float* embed = (const float*)d_in[1];
    const float* W1    = (const float*)d_in[2];
    const float* b1    = (const float*)d_in[3];
    const float* W2    = (const float*)d_in[4];
    const float* b2    = (const float*)d_in[5];
    const float* gamma = (const float*)d_in[6];
    const float* beta  = (const float*)d_in[7];
    const float* Wk    = (const float*)d_in[8];
    const float* Wr    = (const float*)d_in[9];
    const float* br    = (const float*)d_in[10];
    const float* Wo    = (const float*)d_in[11];
    const float* bo    = (const float*)d_in[12];

    float* Kbuf    = (float*)d_ws;                    // 32768 * 128 f32 = 16 MiB
    float* readout = Kbuf + (size_t)TOK_ * H_;        // 128 * 128 f32
    float* out     = (float*)d_out;

    // k_scan dynamic LDS: 128 KiB k-store + 3*256 f32 scalars + 2*4 f32 red
    const size_t scan_lds = 32768 * 4 + 3 * 256 * 4 + 8 * 4;   // 134176 B

    k_ffn <<<TOK_ / 64, 256, 0, stream>>>(seq, embed, W1, b1, W2, b2, gamma, beta, Wk, Kbuf);
    k_scan<<<B_,       256, scan_lds, stream>>>(Kbuf, readout);
    k_out <<<B_,       256, 0, stream>>>(readout, Wr, br, Wo, bo, out);
}